// Round 9
// baseline (310.197 us; speedup 1.0000x reference)
//
#include <hip/hip_runtime.h>

// ---------------------------------------------------------------------------
// SparseAttention fused pipeline for MI355X (gfx950).
//   B=2, S=2048, H=1024, NH=16, HD=64.
// cast f32->bf16 -> threefry mask bitset -> QKV MFMA GEMM (V written
// transposed AND pi-permuted per 64-key tile) -> fused dense-softmax attn.
// Multiplicative mask => masked scores 0 => exp(0)=1 stays in softmax; no
// max-subtraction needed (|s| <= ~3).
// pi(k) = 4*(k&15) + (k>>4) within each 64-key tile, applied consistently to
// P-LDS positions and global Vt layout (PV is permutation-invariant in k).
// P pack: software f2bf (RNE; identical to R2's verified path) into a u16x4
// store; P read as u16x8 + bit_cast + sched_barrier(0) fence.
// [R3 failed: inline-asm cvt_pk operand order / uint2 TBAA suspects — both
//  now eliminated with R2-verified machinery. R4: infra. R5: compile error
//  (__hip_bfloat162 not trivially copyable) — replaced with f2bf.
//  R6/R7/R8: GPU acquisition timeouts, never ran — resubmitted unchanged.]
// ---------------------------------------------------------------------------

typedef unsigned int u32;
typedef unsigned short u16;
typedef float f32x4 __attribute__((ext_vector_type(4)));
typedef short s16x8 __attribute__((ext_vector_type(8)));
typedef u16  u16x8 __attribute__((ext_vector_type(8)));
typedef u32  u32x4 __attribute__((ext_vector_type(4)));
typedef u16  u16x4 __attribute__((ext_vector_type(4)));

__device__ __forceinline__ u16 f2bf(float f) {
  u32 u = __builtin_bit_cast(u32, f);
  return (u16)((u + 0x7FFFu + ((u >> 16) & 1u)) >> 16);   // RNE
}

// async global->LDS, 16B per lane (dest must be wave-uniform base + lane*16)
__device__ __forceinline__ void async16(void* lds, const void* g) {
  __builtin_amdgcn_global_load_lds((const __attribute__((address_space(1))) u32*)g,
                                   (__attribute__((address_space(3))) u32*)lds, 16, 0, 0);
}

// ---------------------------------------------------------------------------
// f32 -> bf16 cast
// ---------------------------------------------------------------------------
__global__ __launch_bounds__(256) void cast_kernel(const float* __restrict__ src,
                                                   u16* __restrict__ dst, int n4) {
  int i = blockIdx.x * 256 + threadIdx.x;
  if (i < n4) {
    float4 v = ((const float4*)src)[i];
    u16x4 o = { f2bf(v.x), f2bf(v.y), f2bf(v.z), f2bf(v.w) };
    ((u16x4*)dst)[i] = o;
  }
}

// ---------------------------------------------------------------------------
// JAX threefry2x32, key = (0, 42)
// ---------------------------------------------------------------------------
__device__ __forceinline__ void threefry(u32 x0, u32 x1, u32& y0, u32& y1) {
  const u32 k0 = 0u, k1 = 42u, k2 = 0u ^ 42u ^ 0x1BD11BDAu;
  x0 += k0; x1 += k1;
#define TFR(r) { x0 += x1; x1 = (x1 << r) | (x1 >> (32 - r)); x1 ^= x0; }
  TFR(13) TFR(15) TFR(26) TFR(6)  x0 += k1; x1 += k2 + 1u;
  TFR(17) TFR(29) TFR(16) TFR(24) x0 += k2; x1 += k0 + 2u;
  TFR(13) TFR(15) TFR(26) TFR(6)  x0 += k0; x1 += k1 + 3u;
  TFR(17) TFR(29) TFR(16) TFR(24) x0 += k1; x1 += k2 + 4u;
  TFR(13) TFR(15) TFR(26) TFR(6)  x0 += k2; x1 += k0 + 5u;
#undef TFR
  y0 = x0; y1 = x1;
}

// ---------------------------------------------------------------------------
// Mask: band(+-2) OR top-204 of partitionable-threefry uniform row.
// bits(i) = y0^y1, counts (0, i). Rank on bits>>9 (monotone); ties -> lower
// col (stable top_k). Output bitset [2048][64] u32.
// ---------------------------------------------------------------------------
#define NRAND 204

__global__ __launch_bounds__(256) void mask_kernel(u32* __restrict__ maskbits) {
  __shared__ u32 hist[256];
  __shared__ u32 mwords[64];
  __shared__ u32 candV[128];
  __shared__ u32 candC[128];
  __shared__ u32 used[128];
  __shared__ u32 scal[4];

  const int tid = threadIdx.x;
  const int row = blockIdx.x;
  hist[tid] = 0;
  if (tid < 64) mwords[tid] = 0;
  if (tid < 128) used[tid] = 0;
  if (tid == 0) scal[2] = 0;
  __syncthreads();

  u32 k23[8];
#pragma unroll
  for (int j = 0; j < 8; ++j) {
    u32 c = (u32)tid * 8u + (u32)j;
    u32 flat = (u32)row * 2048u + c;
    u32 y0, y1; threefry(0u, flat, y0, y1);
    u32 bits = y0 ^ y1;
    k23[j] = bits >> 9;
    atomicAdd(&hist[k23[j] >> 15], 1u);
  }
  __syncthreads();
  for (int off = 1; off < 256; off <<= 1) {
    u32 add = (tid + off < 256) ? hist[tid + off] : 0u;
    __syncthreads();
    hist[tid] += add;
    __syncthreads();
  }
  u32 Sv = hist[tid];
  u32 Sn = (tid < 255) ? hist[tid + 1] : 0u;
  if (Sv >= NRAND && Sn < NRAND) { scal[0] = (u32)tid; scal[1] = NRAND - Sn; }
  __syncthreads();
  const u32 bin = scal[0];
  const u32 need = scal[1];
#pragma unroll
  for (int j = 0; j < 8; ++j) {
    if ((k23[j] >> 15) == bin) {
      u32 p = atomicAdd(&scal[2], 1u);
      if (p < 128u) { candV[p] = k23[j]; candC[p] = (u32)tid * 8u + (u32)j; }
    }
  }
  __syncthreads();
  if (tid == 0) {
    int n = (int)(scal[2] < 128u ? scal[2] : 128u);
    for (u32 t = 0; t < need; ++t) {
      int best = -1;
      for (int i2 = 0; i2 < n; ++i2) {
        if (used[i2]) continue;
        if (best < 0 || candV[i2] > candV[best] ||
            (candV[i2] == candV[best] && candC[i2] < candC[best])) best = i2;
      }
      if (best < 0) break;
      used[best] = 1;
      atomicOr(&mwords[candC[best] >> 5], 1u << (candC[best] & 31u));
    }
  }
#pragma unroll
  for (int j = 0; j < 8; ++j) {
    u32 c = (u32)tid * 8u + (u32)j;
    if ((k23[j] >> 15) > bin) atomicOr(&mwords[c >> 5], 1u << (c & 31u));
  }
  if (tid < 5) {
    int c = row - 2 + tid;
    if (c >= 0 && c < 2048) atomicOr(&mwords[c >> 5], 1u << (c & 31u));
  }
  __syncthreads();
  if (tid < 64) maskbits[row * 64 + tid] = mwords[tid];
}

// ---------------------------------------------------------------------------
// QKV projection (m97-style 128x128, BK=32). z=0: Q (x0.125, [bh][s][d]);
// z=1: K; z=2: V transposed to Vt[bh][d][s'] where s' within each 64-tile is
// pi(s) = 4*(s&15)+(s>>4)  (consumed pi-consistently by attn's P).
// ---------------------------------------------------------------------------
__global__ __launch_bounds__(256) void gemm_qkv(
    const u16* __restrict__ Xbf, const u16* __restrict__ Wbf3,
    const float* __restrict__ bq, const float* __restrict__ bk,
    const float* __restrict__ bv,
    u16* __restrict__ Qbf, u16* __restrict__ Kbf, u16* __restrict__ VtB) {
  __shared__ u16 smem[128 * 136];
  u16* As = smem;                            // [128][32]
  u16* Bs = smem + 4096;                     // [128][32]

  const int tid  = threadIdx.x;
  const int lane = tid & 63;
  const int w    = tid >> 6;
  const int wr = w >> 1, wc = w & 1;
  const int l15 = lane & 15, l4 = lane >> 4;
  const int mBase = blockIdx.x * 128;
  const int nBase = blockIdx.y * 128;
  const int z = blockIdx.z;
  const u16* Bmat = Wbf3 + z * 1048576;
  const float* bias = (z == 0) ? bq : (z == 1) ? bk : bv;

  const int ci1 = tid, ci2 = tid + 256;
  const int r1 = ci1 >> 2, c1 = ci1 & 3, cc1 = c1 ^ ((r1 >> 1) & 3);
  const int r2 = ci2 >> 2, c2 = ci2 & 3, cc2 = c2 ^ ((r2 >> 1) & 3);

  f32x4 acc[4][4];
#pragma unroll
  for (int i = 0; i < 4; ++i)
#pragma unroll
    for (int j = 0; j < 4; ++j) acc[i][j] = {0.f, 0.f, 0.f, 0.f};

  for (int k0 = 0; k0 < 1024; k0 += 32) {
    async16(As + ci1 * 8, Xbf + (mBase + r1) * 1024 + k0 + cc1 * 8);
    async16(As + ci2 * 8, Xbf + (mBase + r2) * 1024 + k0 + cc2 * 8);
    async16(Bs + ci1 * 8, Bmat + (nBase + r1) * 1024 + k0 + cc1 * 8);
    async16(Bs + ci2 * 8, Bmat + (nBase + r2) * 1024 + k0 + cc2 * 8);
    __syncthreads();
    s16x8 a[4], b[4];
#pragma unroll
    for (int f = 0; f < 4; ++f) {
      int rl = wr * 64 + f * 16 + l15;
      a[f] = *(const s16x8*)(As + rl * 32 + ((l4 ^ ((rl >> 1) & 3)) * 8));
    }
#pragma unroll
    for (int f = 0; f < 4; ++f) {
      int rl = wc * 64 + f * 16 + l15;
      b[f] = *(const s16x8*)(Bs + rl * 32 + ((l4 ^ ((rl >> 1) & 3)) * 8));
    }
#pragma unroll
    for (int i = 0; i < 4; ++i)
#pragma unroll
      for (int j = 0; j < 4; ++j)
        acc[i][j] = __builtin_amdgcn_mfma_f32_16x16x32_bf16(a[i], b[j], acc[i][j], 0, 0, 0);
    __syncthreads();
  }

  const float scale = (z == 0) ? 0.125f : 1.0f;
  if (z < 2) {
    u16* dst = (z == 0) ? Qbf : Kbf;
#pragma unroll
    for (int i = 0; i < 4; ++i)
#pragma unroll
      for (int j = 0; j < 4; ++j) {
        int ng = nBase + wc * 64 + j * 16 + l15;
        int h = ng >> 6, d = ng & 63;
        float bb = bias[ng];
#pragma unroll
        for (int r = 0; r < 4; ++r) {
          int mg = mBase + wr * 64 + i * 16 + l4 * 4 + r;
          int bbi = mg >> 11, s = mg & 2047;
          dst[(((bbi * 16 + h) * 2048 + s) * 64) + d] = f2bf((acc[i][j][r] + bb) * scale);
        }
      }
  } else {
    // V: transpose in LDS with per-64-tile pi permutation on the s-dim.
    // s64 = i*16 + l4*4 + r  ->  pi(s64) = 16*l4 + 4*r + i; block = wr.
    u16* ct = smem;
#pragma unroll
    for (int i = 0; i < 4; ++i)
#pragma unroll
      for (int j = 0; j < 4; ++j) {
        int nl = wc * 64 + j * 16 + l15;
        float bb = bias[nBase + nl];
        int base = nl * 136 + wr * 64 + 16 * l4 + i;
#pragma unroll
        for (int r = 0; r < 4; ++r)
          ct[base + 4 * r] = f2bf(acc[i][j][r] + bb);
      }
    __syncthreads();
#pragma unroll
    for (int it = 0; it < 8; ++it) {
      int ci = tid + it * 256;
      int nl = ci >> 4, m8 = ci & 15;
      int ng = nBase + nl, mg = mBase + m8 * 8;
      int h = ng >> 6, d = ng & 63;
      int bbi = mg >> 11, s = mg & 2047;
      s16x8 v = *(const s16x8*)(ct + nl * 136 + m8 * 8);
      *(s16x8*)(VtB + (((bbi * 16 + h) * 64 + d) * 2048) + s) = v;
    }
  }
}

// ---------------------------------------------------------------------------
// Fused attention v2c. Block = 64 q-rows x one bh, 4 waves (16 q-rows each).
//  - K: LDS double-buffered via global_load_lds, 2-phase counted pipeline.
//  - V: direct global 16B fragment loads (zero intra-block reuse; L2-resident;
//       global layout already pi-permuted per tile).
//  - mask: direct global uint2 per (row, kt) (L1 broadcast-merged).
//  - P: f2bf (R2-verified RNE) -> u16x4 LDS store; read u16x8 + bit_cast;
//       sched_barrier(0) fence between write and read.
//  - XCD chunk swizzle: 4 bh per XCD -> K/V working set 2MB fits per-XCD L2.
// ---------------------------------------------------------------------------
__global__ __launch_bounds__(256, 4) void attn_kernel(
    const u16* __restrict__ Qbf, const u16* __restrict__ Kbf,
    const u16* __restrict__ Vt, const u32* __restrict__ maskbits,
    float* __restrict__ out) {
  __shared__ u16 Kb[2][4096];      // [64 keys][64 d], rows XOR-swizzled
  __shared__ u16 Pls[4][1152];     // per-wave P: [16 qrow][64 pi-pos + 8 pad]

  const int tid  = threadIdx.x;
  const int lane = tid & 63;
  const int w    = tid >> 6;
  const int l15 = lane & 15, l4 = lane >> 4;

  // bijective XCD chunk swizzle over the 1024-block grid (1024 % 8 == 0)
  const int lin = blockIdx.x + 32 * blockIdx.y;
  const int wg  = (lin & 7) * 128 + (lin >> 3);
  const int qt = wg & 31;
  const int bh = wg >> 5;
  const int qbase = qt * 64;

  const int qrow = qbase + w * 16 + l15;
  const u16* qp = Qbf + ((bh * 2048 + qrow) * 64) + l4 * 8;
  s16x8 qa0 = *(const s16x8*)(qp);
  s16x8 qa1 = *(const s16x8*)(qp + 32);

  // per-thread mask row pointers (4 C-rows: qrow = w*16 + l4*4 + r)
  const u32* mrow[4];
#pragma unroll
  for (int r = 0; r < 4; ++r)
    mrow[r] = maskbits + (qbase + w * 16 + l4 * 4 + r) * 64;

  // V row pointers (d = df*16 + l15), pi-layout global
  const u16* vrow[4];
#pragma unroll
  for (int df = 0; df < 4; ++df)
    vrow[df] = Vt + (size_t)(bh * 64 + df * 16 + l15) * 2048;

  const f32x4 fzero = {0.f, 0.f, 0.f, 0.f};
  f32x4 acc[4];
#pragma unroll
  for (int d = 0; d < 4; ++d) acc[d] = fzero;
  float rs[4] = {0.f, 0.f, 0.f, 0.f};

  const int rkA = tid >> 3, cA = tid & 7, csA = cA ^ (rkA & 7);
  const int ci2 = tid + 256;
  const int rkB = ci2 >> 3, cB = ci2 & 7, csB = cB ^ (rkB & 7);
  const u16* kgbase = Kbf + (size_t)(bh * 2048) * 64;

  // prologue: stage K tile 0
  async16(Kb[0] + tid * 8, kgbase + rkA * 64 + csA * 8);
  async16(Kb[0] + ci2 * 8, kgbase + rkB * 64 + csB * 8);
  asm volatile("s_waitcnt vmcnt(0)" ::: "memory");
  __syncthreads();

  u16* Pw = Pls[w];

  for (int kt = 0; kt < 32; ++kt) {
    const int kb = kt * 64;
    const int cur = kt & 1;

    // V fragments for this tile (early issue, direct global)
    s16x8 vf0[4], vf1[4];
#pragma unroll
    for (int df = 0; df < 4; ++df) {
      vf0[df] = *(const s16x8*)(vrow[df] + kb + l4 * 8);
      vf1[df] = *(const s16x8*)(vrow[df] + kb + 32 + l4 * 8);
    }
    // mask words for this tile
    uint2 mw2[4];
#pragma unroll
    for (int r = 0; r < 4; ++r)
      mw2[r] = *(const uint2*)(mrow[r] + kt * 2);

    // prefetch next K tile into the other buffer
    if (kt < 31) {
      const u16* kg = kgbase + (kb + 64) * 64;
      async16(Kb[cur ^ 1] + tid * 8, kg + rkA * 64 + csA * 8);
      async16(Kb[cur ^ 1] + ci2 * 8, kg + rkB * 64 + csB * 8);
    }

    // QK^T from Kb[cur]
    f32x4 sc[4];
#pragma unroll
    for (int fn = 0; fn < 4; ++fn) {
      int key = fn * 16 + l15;
      s16x8 kf0 = *(const s16x8*)(Kb[cur] + key * 64 + ((l4 ^ (key & 7)) * 8));
      s16x8 kf1 = *(const s16x8*)(Kb[cur] + key * 64 + (((l4 + 4) ^ (key & 7)) * 8));
      sc[fn] = __builtin_amdgcn_mfma_f32_16x16x32_bf16(qa0, kf0, fzero, 0, 0, 0);
      sc[fn] = __builtin_amdgcn_mfma_f32_16x16x32_bf16(qa1, kf1, sc[fn], 0, 0, 0);
    }

    // mask * exp, packed P write (keys fn*16+l15 -> pi-pos 4*l15 + fn)
#pragma unroll
    for (int r = 0; r < 4; ++r) {
      float p[4];
#pragma unroll
      for (int fn = 0; fn < 4; ++fn) {
        u32 word = (fn < 2) ? mw2[r].x : mw2[r].y;
        u32 bp = (u32)((fn & 1) * 16 + l15);
        float sv = ((word >> bp) & 1u) ? sc[fn][r] : 0.0f;
        p[fn] = __expf(sv);
      }
      rs[r] += (p[0] + p[1]) + (p[2] + p[3]);
      u16x4 pk = { f2bf(p[0]), f2bf(p[1]), f2bf(p[2]), f2bf(p[3]) };
      *(u16x4*)(Pw + (l4 * 4 + r) * 72 + l15 * 4) = pk;
    }

    __builtin_amdgcn_sched_barrier(0);   // order P writes before P reads

    // PV (A = P from per-wave LDS, B = V regs)
    u16x8 t0 = *(const u16x8*)(Pw + l15 * 72 + l4 * 8);
    u16x8 t1 = *(const u16x8*)(Pw + l15 * 72 + 32 + l4 * 8);
    s16x8 pa0 = __builtin_bit_cast(s16x8, t0);
    s16x8 pa1 = __builtin_bit_cast(s16x8, t1);
#pragma unroll
    for (int df = 0; df < 4; ++df) {
      acc[df] = __builtin_amdgcn_mfma_f32_16x16x32_bf16(pa0, vf0[df], acc[df], 0, 0, 0);
      acc[df] = __builtin_amdgcn_mfma_f32_16x16x32_bf16(pa1, vf1[df], acc[df], 0, 0, 0);
    }

    asm volatile("s_waitcnt vmcnt(0)" ::: "memory");   // next K tile staged
    __syncthreads();
  }

#pragma unroll
  for (int r = 0; r < 4; ++r) {
    float v = rs[r];
    v += __shfl_xor(v, 1); v += __shfl_xor(v, 2);
    v += __shfl_xor(v, 4); v += __shfl_xor(v, 8);
    rs[r] = 1.0f / v;
  }
  const int b = bh >> 4, h = bh & 15;
#pragma unroll
  for (int df = 0; df < 4; ++df) {
    int col = h * 64 + df * 16 + l15;
#pragma unroll
    for (int r = 0; r < 4; ++r) {
      int qg = qbase + w * 16 + l4 * 4 + r;
      out[(b * 2048 + qg) * 1024 + col] = acc[df][r] * rs[r];
    }
  }
}

// ---------------------------------------------------------------------------
extern "C" void kernel_launch(void* const* d_in, const int* in_sizes, int n_in,
                              void* d_out, int out_size, void* d_ws, size_t ws_size,
                              hipStream_t stream) {
  const float* hs = (const float*)d_in[0];
  const float* Wq = (const float*)d_in[1];
  const float* bq = (const float*)d_in[2];
  const float* Wk = (const float*)d_in[3];
  const float* bk = (const float*)d_in[4];
  const float* Wv = (const float*)d_in[5];
  const float* bv = (const float*)d_in[6];
  float* out = (float*)d_out;
  char* ws = (char*)d_ws;

  u32* maskbits = (u32*)(ws);                       // 512 KB
  u16* Xbf  = (u16*)(ws + 524288);                  // 8 MB  [4096][1024]
  u16* Wbf3 = (u16*)(ws + 524288 + 8388608);        // 6 MB  3x[1024][1024]
  u16* Qbf  = (u16*)(ws + 15204352);                // 8 MB  [bh][s][d]
  u16* Kbf  = (u16*)(ws + 23592960);                // 8 MB  [bh][s][d]
  u16* Vt   = (u16*)(ws + 31981568);                // 8 MB  [bh][d][s'] pi-layout

  cast_kernel<<<4096, 256, 0, stream>>>(hs, Xbf, 1048576);
  cast_kernel<<<1024, 256, 0, stream>>>(Wq, Wbf3,           262144);
  cast_kernel<<<1024, 256, 0, stream>>>(Wk, Wbf3 + 1048576, 262144);
  cast_kernel<<<1024, 256, 0, stream>>>(Wv, Wbf3 + 2097152, 262144);
  mask_kernel<<<2048, 256, 0, stream>>>(maskbits);
  gemm_qkv<<<dim3(32, 8, 3), 256, 0, stream>>>(Xbf, Wbf3, bq, bk, bv, Qbf, Kbf, Vt);
  attn_kernel<<<dim3(32, 32), 256, 0, stream>>>(Qbf, Kbf, Vt, maskbits, out);
}

// Round 10
// 250.923 us; speedup vs baseline: 1.2362x; 1.2362x over previous
//
#include <hip/hip_runtime.h>

// ---------------------------------------------------------------------------
// SparseAttention fused pipeline for MI355X (gfx950).
//   B=2, S=2048, H=1024, NH=16, HD=64.
// cast f32->bf16 -> threefry mask bitset -> QKV MFMA GEMM (V written
// transposed AND pi-permuted per 64-key tile) -> fused dense-softmax attn.
// Multiplicative mask => masked scores 0 => exp(0)=1 stays in softmax.
// pi(k) = 4*(k&15) + (k>>4) per 64-key tile, applied consistently to P-LDS
// and global Vt (PV is permutation-invariant in k).  [verified R9, 2.44e-4]
// R9 lesson: V-direct-from-global regressed attn 92.7->154.7us (scatter
// 4KB-apart lanes, ~16 txns/load, latency exposed by per-iter barrier;
// busy% 60->35). This round: V back to LDS staging (R2-verified read path)
// but DOUBLE-BUFFERED with K (R9-verified prefetch pattern) -> overlap that
// R2 lacked, without R9's V-latency exposure.
// ---------------------------------------------------------------------------

typedef unsigned int u32;
typedef unsigned short u16;
typedef float f32x4 __attribute__((ext_vector_type(4)));
typedef short s16x8 __attribute__((ext_vector_type(8)));
typedef u16  u16x8 __attribute__((ext_vector_type(8)));
typedef u32  u32x4 __attribute__((ext_vector_type(4)));
typedef u16  u16x4 __attribute__((ext_vector_type(4)));

__device__ __forceinline__ u16 f2bf(float f) {
  u32 u = __builtin_bit_cast(u32, f);
  return (u16)((u + 0x7FFFu + ((u >> 16) & 1u)) >> 16);   // RNE
}

// async global->LDS, 16B per lane (dest must be wave-uniform base + lane*16)
__device__ __forceinline__ void async16(void* lds, const void* g) {
  __builtin_amdgcn_global_load_lds((const __attribute__((address_space(1))) u32*)g,
                                   (__attribute__((address_space(3))) u32*)lds, 16, 0, 0);
}

// ---------------------------------------------------------------------------
// f32 -> bf16 cast
// ---------------------------------------------------------------------------
__global__ __launch_bounds__(256) void cast_kernel(const float* __restrict__ src,
                                                   u16* __restrict__ dst, int n4) {
  int i = blockIdx.x * 256 + threadIdx.x;
  if (i < n4) {
    float4 v = ((const float4*)src)[i];
    u16x4 o = { f2bf(v.x), f2bf(v.y), f2bf(v.z), f2bf(v.w) };
    ((u16x4*)dst)[i] = o;
  }
}

// ---------------------------------------------------------------------------
// JAX threefry2x32, key = (0, 42)
// ---------------------------------------------------------------------------
__device__ __forceinline__ void threefry(u32 x0, u32 x1, u32& y0, u32& y1) {
  const u32 k0 = 0u, k1 = 42u, k2 = 0u ^ 42u ^ 0x1BD11BDAu;
  x0 += k0; x1 += k1;
#define TFR(r) { x0 += x1; x1 = (x1 << r) | (x1 >> (32 - r)); x1 ^= x0; }
  TFR(13) TFR(15) TFR(26) TFR(6)  x0 += k1; x1 += k2 + 1u;
  TFR(17) TFR(29) TFR(16) TFR(24) x0 += k2; x1 += k0 + 2u;
  TFR(13) TFR(15) TFR(26) TFR(6)  x0 += k0; x1 += k1 + 3u;
  TFR(17) TFR(29) TFR(16) TFR(24) x0 += k1; x1 += k2 + 4u;
  TFR(13) TFR(15) TFR(26) TFR(6)  x0 += k2; x1 += k0 + 5u;
#undef TFR
  y0 = x0; y1 = x1;
}

// ---------------------------------------------------------------------------
// Mask: band(+-2) OR top-204 of partitionable-threefry uniform row.
// bits(i) = y0^y1, counts (0, i). Rank on bits>>9 (monotone); ties -> lower
// col (stable top_k). Output bitset [2048][64] u32.
// ---------------------------------------------------------------------------
#define NRAND 204

__global__ __launch_bounds__(256) void mask_kernel(u32* __restrict__ maskbits) {
  __shared__ u32 hist[256];
  __shared__ u32 mwords[64];
  __shared__ u32 candV[128];
  __shared__ u32 candC[128];
  __shared__ u32 used[128];
  __shared__ u32 scal[4];

  const int tid = threadIdx.x;
  const int row = blockIdx.x;
  hist[tid] = 0;
  if (tid < 64) mwords[tid] = 0;
  if (tid < 128) used[tid] = 0;
  if (tid == 0) scal[2] = 0;
  __syncthreads();

  u32 k23[8];
#pragma unroll
  for (int j = 0; j < 8; ++j) {
    u32 c = (u32)tid * 8u + (u32)j;
    u32 flat = (u32)row * 2048u + c;
    u32 y0, y1; threefry(0u, flat, y0, y1);
    u32 bits = y0 ^ y1;
    k23[j] = bits >> 9;
    atomicAdd(&hist[k23[j] >> 15], 1u);
  }
  __syncthreads();
  for (int off = 1; off < 256; off <<= 1) {
    u32 add = (tid + off < 256) ? hist[tid + off] : 0u;
    __syncthreads();
    hist[tid] += add;
    __syncthreads();
  }
  u32 Sv = hist[tid];
  u32 Sn = (tid < 255) ? hist[tid + 1] : 0u;
  if (Sv >= NRAND && Sn < NRAND) { scal[0] = (u32)tid; scal[1] = NRAND - Sn; }
  __syncthreads();
  const u32 bin = scal[0];
  const u32 need = scal[1];
#pragma unroll
  for (int j = 0; j < 8; ++j) {
    if ((k23[j] >> 15) == bin) {
      u32 p = atomicAdd(&scal[2], 1u);
      if (p < 128u) { candV[p] = k23[j]; candC[p] = (u32)tid * 8u + (u32)j; }
    }
  }
  __syncthreads();
  if (tid == 0) {
    int n = (int)(scal[2] < 128u ? scal[2] : 128u);
    for (u32 t = 0; t < need; ++t) {
      int best = -1;
      for (int i2 = 0; i2 < n; ++i2) {
        if (used[i2]) continue;
        if (best < 0 || candV[i2] > candV[best] ||
            (candV[i2] == candV[best] && candC[i2] < candC[best])) best = i2;
      }
      if (best < 0) break;
      used[best] = 1;
      atomicOr(&mwords[candC[best] >> 5], 1u << (candC[best] & 31u));
    }
  }
#pragma unroll
  for (int j = 0; j < 8; ++j) {
    u32 c = (u32)tid * 8u + (u32)j;
    if ((k23[j] >> 15) > bin) atomicOr(&mwords[c >> 5], 1u << (c & 31u));
  }
  if (tid < 5) {
    int c = row - 2 + tid;
    if (c >= 0 && c < 2048) atomicOr(&mwords[c >> 5], 1u << (c & 31u));
  }
  __syncthreads();
  if (tid < 64) maskbits[row * 64 + tid] = mwords[tid];
}

// ---------------------------------------------------------------------------
// QKV projection (m97-style 128x128, BK=32). z=0: Q (x0.125, [bh][s][d]);
// z=1: K; z=2: V transposed to Vt[bh][d][s'] where s' within each 64-tile is
// pi(s) = 4*(s&15)+(s>>4)  (consumed pi-consistently by attn's P).
// ---------------------------------------------------------------------------
__global__ __launch_bounds__(256) void gemm_qkv(
    const u16* __restrict__ Xbf, const u16* __restrict__ Wbf3,
    const float* __restrict__ bq, const float* __restrict__ bk,
    const float* __restrict__ bv,
    u16* __restrict__ Qbf, u16* __restrict__ Kbf, u16* __restrict__ VtB) {
  __shared__ u16 smem[128 * 136];
  u16* As = smem;                            // [128][32]
  u16* Bs = smem + 4096;                     // [128][32]

  const int tid  = threadIdx.x;
  const int lane = tid & 63;
  const int w    = tid >> 6;
  const int wr = w >> 1, wc = w & 1;
  const int l15 = lane & 15, l4 = lane >> 4;
  const int mBase = blockIdx.x * 128;
  const int nBase = blockIdx.y * 128;
  const int z = blockIdx.z;
  const u16* Bmat = Wbf3 + z * 1048576;
  const float* bias = (z == 0) ? bq : (z == 1) ? bk : bv;

  const int ci1 = tid, ci2 = tid + 256;
  const int r1 = ci1 >> 2, c1 = ci1 & 3, cc1 = c1 ^ ((r1 >> 1) & 3);
  const int r2 = ci2 >> 2, c2 = ci2 & 3, cc2 = c2 ^ ((r2 >> 1) & 3);

  f32x4 acc[4][4];
#pragma unroll
  for (int i = 0; i < 4; ++i)
#pragma unroll
    for (int j = 0; j < 4; ++j) acc[i][j] = {0.f, 0.f, 0.f, 0.f};

  for (int k0 = 0; k0 < 1024; k0 += 32) {
    async16(As + ci1 * 8, Xbf + (mBase + r1) * 1024 + k0 + cc1 * 8);
    async16(As + ci2 * 8, Xbf + (mBase + r2) * 1024 + k0 + cc2 * 8);
    async16(Bs + ci1 * 8, Bmat + (nBase + r1) * 1024 + k0 + cc1 * 8);
    async16(Bs + ci2 * 8, Bmat + (nBase + r2) * 1024 + k0 + cc2 * 8);
    __syncthreads();
    s16x8 a[4], b[4];
#pragma unroll
    for (int f = 0; f < 4; ++f) {
      int rl = wr * 64 + f * 16 + l15;
      a[f] = *(const s16x8*)(As + rl * 32 + ((l4 ^ ((rl >> 1) & 3)) * 8));
    }
#pragma unroll
    for (int f = 0; f < 4; ++f) {
      int rl = wc * 64 + f * 16 + l15;
      b[f] = *(const s16x8*)(Bs + rl * 32 + ((l4 ^ ((rl >> 1) & 3)) * 8));
    }
#pragma unroll
    for (int i = 0; i < 4; ++i)
#pragma unroll
      for (int j = 0; j < 4; ++j)
        acc[i][j] = __builtin_amdgcn_mfma_f32_16x16x32_bf16(a[i], b[j], acc[i][j], 0, 0, 0);
    __syncthreads();
  }

  const float scale = (z == 0) ? 0.125f : 1.0f;
  if (z < 2) {
    u16* dst = (z == 0) ? Qbf : Kbf;
#pragma unroll
    for (int i = 0; i < 4; ++i)
#pragma unroll
      for (int j = 0; j < 4; ++j) {
        int ng = nBase + wc * 64 + j * 16 + l15;
        int h = ng >> 6, d = ng & 63;
        float bb = bias[ng];
#pragma unroll
        for (int r = 0; r < 4; ++r) {
          int mg = mBase + wr * 64 + i * 16 + l4 * 4 + r;
          int bbi = mg >> 11, s = mg & 2047;
          dst[(((bbi * 16 + h) * 2048 + s) * 64) + d] = f2bf((acc[i][j][r] + bb) * scale);
        }
      }
  } else {
    // V: transpose in LDS with per-64-tile pi permutation on the s-dim.
    // s64 = i*16 + l4*4 + r  ->  pi(s64) = 16*l4 + 4*r + i; block = wr.
    u16* ct = smem;
#pragma unroll
    for (int i = 0; i < 4; ++i)
#pragma unroll
      for (int j = 0; j < 4; ++j) {
        int nl = wc * 64 + j * 16 + l15;
        float bb = bias[nBase + nl];
        int base = nl * 136 + wr * 64 + 16 * l4 + i;
#pragma unroll
        for (int r = 0; r < 4; ++r)
          ct[base + 4 * r] = f2bf(acc[i][j][r] + bb);
      }
    __syncthreads();
#pragma unroll
    for (int it = 0; it < 8; ++it) {
      int ci = tid + it * 256;
      int nl = ci >> 4, m8 = ci & 15;
      int ng = nBase + nl, mg = mBase + m8 * 8;
      int h = ng >> 6, d = ng & 63;
      int bbi = mg >> 11, s = mg & 2047;
      s16x8 v = *(const s16x8*)(ct + nl * 136 + m8 * 8);
      *(s16x8*)(VtB + (((bbi * 16 + h) * 64 + d) * 2048) + s) = v;
    }
  }
}

// ---------------------------------------------------------------------------
// Fused attention v3. Block = 64 q-rows x one bh, 4 waves (16 q-rows each).
//  - K AND V: LDS double-buffered via global_load_lds (T3 minimum pipeline:
//    stage kt+1 -> compute kt -> vmcnt(0)+barrier). R2-verified read paths.
//  - mask: direct global uint2 per (row, kt).
//  - P: f2bf -> u16x4 LDS store; read u16x8 + bit_cast; sched_barrier(0)
//    fence between write and read.  [R9-verified]
//  - XCD chunk swizzle: 4 bh per XCD -> K/V L2-resident.  [R9-verified]
// LDS: Kb 16KB + Vb 16KB + Pls 9KB = 41984 B -> 3 blocks/CU.
// ---------------------------------------------------------------------------
__global__ __launch_bounds__(256, 4) void attn_kernel(
    const u16* __restrict__ Qbf, const u16* __restrict__ Kbf,
    const u16* __restrict__ Vt, const u32* __restrict__ maskbits,
    float* __restrict__ out) {
  __shared__ u16 Kb[2][4096];      // [64 keys][64 d], rows XOR-swizzled
  __shared__ u16 Vb[2][4096];      // [64 d][64 pi-keys], rows XOR-swizzled
  __shared__ u16 Pls[4][1152];     // per-wave P: [16 qrow][64 pi-pos + 8 pad]

  const int tid  = threadIdx.x;
  const int lane = tid & 63;
  const int w    = tid >> 6;
  const int l15 = lane & 15, l4 = lane >> 4;

  // bijective XCD chunk swizzle over the 1024-block grid (1024 % 8 == 0)
  const int lin = blockIdx.x + 32 * blockIdx.y;
  const int wg  = (lin & 7) * 128 + (lin >> 3);
  const int qt = wg & 31;
  const int bh = wg >> 5;
  const int qbase = qt * 64;

  const int qrow = qbase + w * 16 + l15;
  const u16* qp = Qbf + ((bh * 2048 + qrow) * 64) + l4 * 8;
  s16x8 qa0 = *(const s16x8*)(qp);
  s16x8 qa1 = *(const s16x8*)(qp + 32);

  // per-thread mask row pointers (4 C-rows: qrow = w*16 + l4*4 + r)
  const u32* mrow[4];
#pragma unroll
  for (int r = 0; r < 4; ++r)
    mrow[r] = maskbits + (qbase + w * 16 + l4 * 4 + r) * 64;

  const f32x4 fzero = {0.f, 0.f, 0.f, 0.f};
  f32x4 acc[4];
#pragma unroll
  for (int d = 0; d < 4; ++d) acc[d] = fzero;
  float rs[4] = {0.f, 0.f, 0.f, 0.f};

  const int rkA = tid >> 3, cA = tid & 7, csA = cA ^ (rkA & 7);
  const int ci2 = tid + 256;
  const int rkB = ci2 >> 3, cB = ci2 & 7, csB = cB ^ (rkB & 7);
  const u16* kgbase = Kbf + (size_t)(bh * 2048) * 64;
  const u16* vgbase = Vt + (size_t)(bh * 64) * 2048;

  // prologue: stage K+V tile 0
  async16(Kb[0] + tid * 8, kgbase + rkA * 64 + csA * 8);
  async16(Kb[0] + ci2 * 8, kgbase + rkB * 64 + csB * 8);
  async16(Vb[0] + tid * 8, vgbase + rkA * 2048 + csA * 8);
  async16(Vb[0] + ci2 * 8, vgbase + rkB * 2048 + csB * 8);
  asm volatile("s_waitcnt vmcnt(0)" ::: "memory");
  __syncthreads();

  u16* Pw = Pls[w];

  for (int kt = 0; kt < 32; ++kt) {
    const int kb = kt * 64;
    const int cur = kt & 1;

    // mask words for this tile
    uint2 mw2[4];
#pragma unroll
    for (int r = 0; r < 4; ++r)
      mw2[r] = *(const uint2*)(mrow[r] + kt * 2);

    // prefetch next K+V tile into the other buffer (flies during compute)
    if (kt < 31) {
      const u16* kg = kgbase + (kb + 64) * 64;
      const u16* vg = vgbase + kb + 64;
      async16(Kb[cur ^ 1] + tid * 8, kg + rkA * 64 + csA * 8);
      async16(Kb[cur ^ 1] + ci2 * 8, kg + rkB * 64 + csB * 8);
      async16(Vb[cur ^ 1] + tid * 8, vg + rkA * 2048 + csA * 8);
      async16(Vb[cur ^ 1] + ci2 * 8, vg + rkB * 2048 + csB * 8);
    }

    // QK^T from Kb[cur]
    f32x4 sc[4];
#pragma unroll
    for (int fn = 0; fn < 4; ++fn) {
      int key = fn * 16 + l15;
      s16x8 kf0 = *(const s16x8*)(Kb[cur] + key * 64 + ((l4 ^ (key & 7)) * 8));
      s16x8 kf1 = *(const s16x8*)(Kb[cur] + key * 64 + (((l4 + 4) ^ (key & 7)) * 8));
      sc[fn] = __builtin_amdgcn_mfma_f32_16x16x32_bf16(qa0, kf0, fzero, 0, 0, 0);
      sc[fn] = __builtin_amdgcn_mfma_f32_16x16x32_bf16(qa1, kf1, sc[fn], 0, 0, 0);
    }

    // mask * exp, packed P write (keys fn*16+l15 -> pi-pos 4*l15 + fn)
#pragma unroll
    for (int r = 0; r < 4; ++r) {
      float p[4];
#pragma unroll
      for (int fn = 0; fn < 4; ++fn) {
        u32 word = (fn < 2) ? mw2[r].x : mw2[r].y;
        u32 bp = (u32)((fn & 1) * 16 + l15);
        float sv = ((word >> bp) & 1u) ? sc[fn][r] : 0.0f;
        p[fn] = __expf(sv);
      }
      rs[r] += (p[0] + p[1]) + (p[2] + p[3]);
      u16x4 pk = { f2bf(p[0]), f2bf(p[1]), f2bf(p[2]), f2bf(p[3]) };
      *(u16x4*)(Pw + (l4 * 4 + r) * 72 + l15 * 4) = pk;
    }

    __builtin_amdgcn_sched_barrier(0);   // order P writes before P reads

    // PV (A = P from per-wave LDS, B = V from Vb[cur], R2-verified pattern)
    u16x8 t0 = *(const u16x8*)(Pw + l15 * 72 + l4 * 8);
    u16x8 t1 = *(const u16x8*)(Pw + l15 * 72 + 32 + l4 * 8);
    s16x8 pa0 = __builtin_bit_cast(s16x8, t0);
    s16x8 pa1 = __builtin_bit_cast(s16x8, t1);
#pragma unroll
    for (int df = 0; df < 4; ++df) {
      int dl = df * 16 + l15;
      s16x8 vf0 = *(const s16x8*)(Vb[cur] + dl * 64 + ((l4 ^ (dl & 7)) * 8));
      s16x8 vf1 = *(const s16x8*)(Vb[cur] + dl * 64 + (((l4 + 4) ^ (dl & 7)) * 8));
      acc[df] = __builtin_amdgcn_mfma_f32_16x16x32_bf16(pa0, vf0, acc[df], 0, 0, 0);
      acc[df] = __builtin_amdgcn_mfma_f32_16x16x32_bf16(pa1, vf1, acc[df], 0, 0, 0);
    }

    asm volatile("s_waitcnt vmcnt(0)" ::: "memory");   // next K+V tile staged
    __syncthreads();
  }

#pragma unroll
  for (int r = 0; r < 4; ++r) {
    float v = rs[r];
    v += __shfl_xor(v, 1); v += __shfl_xor(v, 2);
    v += __shfl_xor(v, 4); v += __shfl_xor(v, 8);
    rs[r] = 1.0f / v;
  }
  const int b = bh >> 4, h = bh & 15;
#pragma unroll
  for (int df = 0; df < 4; ++df) {
    int col = h * 64 + df * 16 + l15;
#pragma unroll
    for (int r = 0; r < 4; ++r) {
      int qg = qbase + w * 16 + l4 * 4 + r;
      out[(b * 2048 + qg) * 1024 + col] = acc[df][r] * rs[r];
    }
  }
}

// ---------------------------------------------------------------------------
extern "C" void kernel_launch(void* const* d_in, const int* in_sizes, int n_in,
                              void* d_out, int out_size, void* d_ws, size_t ws_size,
                              hipStream_t stream) {
  const float* hs = (const float*)d_in[0];
  const float* Wq = (const float*)d_in[1];
  const float* bq = (const float*)d_in[2];
  const float* Wk = (const float*)d_in[3];
  const float* bk = (const float*)d_in[4];
  const float* Wv = (const float*)d_in[5];
  const float* bv = (const float*)d_in[6];
  float* out = (float*)d_out;
  char* ws = (char*)d_ws;

  u32* maskbits = (u32*)(ws);                       // 512 KB
  u16* Xbf  = (u16*)(ws + 524288);                  // 8 MB  [4096][1024]
  u16* Wbf3 = (u16*)(ws + 524288 + 8388608);        // 6 MB  3x[1024][1024]
  u16* Qbf  = (u16*)(ws + 15204352);                // 8 MB  [bh][s][d]
  u16* Kbf  = (u16*)(ws + 23592960);                // 8 MB  [bh][s][d]
  u16* Vt   = (u16*)(ws + 31981568);                // 8 MB  [bh][d][s'] pi-layout

  cast_kernel<<<4096, 256, 0, stream>>>(hs, Xbf, 1048576);
  cast_kernel<<<1024, 256, 0, stream>>>(Wq, Wbf3,           262144);
  cast_kernel<<<1024, 256, 0, stream>>>(Wk, Wbf3 + 1048576, 262144);
  cast_kernel<<<1024, 256, 0, stream>>>(Wv, Wbf3 + 2097152, 262144);
  mask_kernel<<<2048, 256, 0, stream>>>(maskbits);
  gemm_qkv<<<dim3(32, 8, 3), 256, 0, stream>>>(Xbf, Wbf3, bq, bk, bv, Qbf, Kbf, Vt);
  attn_kernel<<<dim3(32, 32), 256, 0, stream>>>(Qbf, Kbf, Vt, maskbits, out);
}

// Round 12
// 250.905 us; speedup vs baseline: 1.2363x; 1.0001x over previous
//
#include <hip/hip_runtime.h>

// ---------------------------------------------------------------------------
// SparseAttention fused pipeline for MI355X (gfx950).
//   B=2, S=2048, H=1024, NH=16, HD=64.
// cast f32->bf16 (merged) -> threefry mask bitset -> QKV MFMA GEMM
// (XCD-swizzled; V transposed + pi-permuted) -> fused dense-softmax attn
// (K+V LDS double-buffered).
// Multiplicative mask => masked scores 0 => exp(0)=1 stays in softmax.
// pi(k) = 4*(k&15)+(k>>4) per 64-key tile on P-LDS and Vt. [R9/R10 verified]
// R11 lesson: cvt_pk asm + uint2-struct-write/u32x4-vector-read failed at
// 6.2e-3 (operand-order or struct-vs-vector TBAA hoist; sched_barrier does
// not block IR-level reordering). This round: TRUNCATION pack in plain C
// ((bits>>16) | (bits & 0xffff0000)) — 2 ops/pair, no asm, no rounding
// sequence — into u32 LDS written with SCALAR u32 stores (same element type
// as the u32x4 read => TBAA-sound). Masked p=1.0 exact; truncation on ~205
// unmasked keys/row adds <6e-5 absmax (4x under threshold with 2.44e-4 base).
// ---------------------------------------------------------------------------

typedef unsigned int u32;
typedef unsigned short u16;
typedef float f32x4 __attribute__((ext_vector_type(4)));
typedef short s16x8 __attribute__((ext_vector_type(8)));
typedef u32  u32x4 __attribute__((ext_vector_type(4)));
typedef u16  u16x4 __attribute__((ext_vector_type(4)));

__device__ __forceinline__ u16 f2bf(float f) {
  u32 u = __builtin_bit_cast(u32, f);
  return (u16)((u + 0x7FFFu + ((u >> 16) & 1u)) >> 16);   // RNE
}

// async global->LDS, 16B per lane (dest must be wave-uniform base + lane*16)
__device__ __forceinline__ void async16(void* lds, const void* g) {
  __builtin_amdgcn_global_load_lds((const __attribute__((address_space(1))) u32*)g,
                                   (__attribute__((address_space(3))) u32*)lds, 16, 0, 0);
}

// ---------------------------------------------------------------------------
// f32 -> bf16 cast, all four tensors in one launch.
// X: blocks [0,4096); Wq/Wk/Wv: 1024 blocks each. Sizes are exact multiples.
// ---------------------------------------------------------------------------
__global__ __launch_bounds__(256) void cast_all(
    const float* __restrict__ hs, const float* __restrict__ Wq,
    const float* __restrict__ Wk, const float* __restrict__ Wv,
    u16* __restrict__ Xbf, u16* __restrict__ Wbf3) {
  const int b = blockIdx.x;
  const float* src;
  u16* dst;
  int i;
  if (b < 4096)      { src = hs; dst = Xbf;            i = b * 256 + threadIdx.x; }
  else if (b < 5120) { src = Wq; dst = Wbf3;           i = (b - 4096) * 256 + threadIdx.x; }
  else if (b < 6144) { src = Wk; dst = Wbf3 + 1048576; i = (b - 5120) * 256 + threadIdx.x; }
  else               { src = Wv; dst = Wbf3 + 2097152; i = (b - 6144) * 256 + threadIdx.x; }
  float4 v = ((const float4*)src)[i];
  u16x4 o = { f2bf(v.x), f2bf(v.y), f2bf(v.z), f2bf(v.w) };
  ((u16x4*)dst)[i] = o;
}

// ---------------------------------------------------------------------------
// JAX threefry2x32, key = (0, 42)
// ---------------------------------------------------------------------------
__device__ __forceinline__ void threefry(u32 x0, u32 x1, u32& y0, u32& y1) {
  const u32 k0 = 0u, k1 = 42u, k2 = 0u ^ 42u ^ 0x1BD11BDAu;
  x0 += k0; x1 += k1;
#define TFR(r) { x0 += x1; x1 = (x1 << r) | (x1 >> (32 - r)); x1 ^= x0; }
  TFR(13) TFR(15) TFR(26) TFR(6)  x0 += k1; x1 += k2 + 1u;
  TFR(17) TFR(29) TFR(16) TFR(24) x0 += k2; x1 += k0 + 2u;
  TFR(13) TFR(15) TFR(26) TFR(6)  x0 += k0; x1 += k1 + 3u;
  TFR(17) TFR(29) TFR(16) TFR(24) x0 += k1; x1 += k2 + 4u;
  TFR(13) TFR(15) TFR(26) TFR(6)  x0 += k2; x1 += k0 + 5u;
#undef TFR
  y0 = x0; y1 = x1;
}

// ---------------------------------------------------------------------------
// Mask: band(+-2) OR top-204 of partitionable-threefry uniform row.
// bits(i) = y0^y1, counts (0, i). Rank on bits>>9 (monotone); ties -> lower
// col (stable top_k). Output bitset [2048][64] u32.
// ---------------------------------------------------------------------------
#define NRAND 204

__global__ __launch_bounds__(256) void mask_kernel(u32* __restrict__ maskbits) {
  __shared__ u32 hist[256];
  __shared__ u32 mwords[64];
  __shared__ u32 candV[128];
  __shared__ u32 candC[128];
  __shared__ u32 used[128];
  __shared__ u32 scal[4];

  const int tid = threadIdx.x;
  const int row = blockIdx.x;
  hist[tid] = 0;
  if (tid < 64) mwords[tid] = 0;
  if (tid < 128) used[tid] = 0;
  if (tid == 0) scal[2] = 0;
  __syncthreads();

  u32 k23[8];
#pragma unroll
  for (int j = 0; j < 8; ++j) {
    u32 c = (u32)tid * 8u + (u32)j;
    u32 flat = (u32)row * 2048u + c;
    u32 y0, y1; threefry(0u, flat, y0, y1);
    u32 bits = y0 ^ y1;
    k23[j] = bits >> 9;
    atomicAdd(&hist[k23[j] >> 15], 1u);
  }
  __syncthreads();
  for (int off = 1; off < 256; off <<= 1) {
    u32 add = (tid + off < 256) ? hist[tid + off] : 0u;
    __syncthreads();
    hist[tid] += add;
    __syncthreads();
  }
  u32 Sv = hist[tid];
  u32 Sn = (tid < 255) ? hist[tid + 1] : 0u;
  if (Sv >= NRAND && Sn < NRAND) { scal[0] = (u32)tid; scal[1] = NRAND - Sn; }
  __syncthreads();
  const u32 bin = scal[0];
  const u32 need = scal[1];
#pragma unroll
  for (int j = 0; j < 8; ++j) {
    if ((k23[j] >> 15) == bin) {
      u32 p = atomicAdd(&scal[2], 1u);
      if (p < 128u) { candV[p] = k23[j]; candC[p] = (u32)tid * 8u + (u32)j; }
    }
  }
  __syncthreads();
  if (tid == 0) {
    int n = (int)(scal[2] < 128u ? scal[2] : 128u);
    for (u32 t = 0; t < need; ++t) {
      int best = -1;
      for (int i2 = 0; i2 < n; ++i2) {
        if (used[i2]) continue;
        if (best < 0 || candV[i2] > candV[best] ||
            (candV[i2] == candV[best] && candC[i2] < candC[best])) best = i2;
      }
      if (best < 0) break;
      used[best] = 1;
      atomicOr(&mwords[candC[best] >> 5], 1u << (candC[best] & 31u));
    }
  }
#pragma unroll
  for (int j = 0; j < 8; ++j) {
    u32 c = (u32)tid * 8u + (u32)j;
    if ((k23[j] >> 15) > bin) atomicOr(&mwords[c >> 5], 1u << (c & 31u));
  }
  if (tid < 5) {
    int c = row - 2 + tid;
    if (c >= 0 && c < 2048) atomicOr(&mwords[c >> 5], 1u << (c & 31u));
  }
  __syncthreads();
  if (tid < 64) maskbits[row * 64 + tid] = mwords[tid];
}

// ---------------------------------------------------------------------------
// QKV projection (m97-style 128x128, BK=32), XCD chunk-swizzled grid.
// z=0: Q (x0.125, [bh][s][d]); z=1: K; z=2: V transposed to Vt[bh][d][s'],
// s' = pi(s) per 64-tile (consumed pi-consistently by attn's P).
// ---------------------------------------------------------------------------
__global__ __launch_bounds__(256) void gemm_qkv(
    const u16* __restrict__ Xbf, const u16* __restrict__ Wbf3,
    const float* __restrict__ bq, const float* __restrict__ bk,
    const float* __restrict__ bv,
    u16* __restrict__ Qbf, u16* __restrict__ Kbf, u16* __restrict__ VtB) {
  __shared__ u16 smem[128 * 136];
  u16* As = smem;                            // [128][32]
  u16* Bs = smem + 4096;                     // [128][32]

  const int tid  = threadIdx.x;
  const int lane = tid & 63;
  const int w    = tid >> 6;
  const int wr = w >> 1, wc = w & 1;
  const int l15 = lane & 15, l4 = lane >> 4;

  // bijective XCD chunk swizzle over the 768-block grid (768 % 8 == 0)
  const int lin = blockIdx.x + 32 * (blockIdx.y + 8 * blockIdx.z);
  const int wg  = (lin & 7) * 96 + (lin >> 3);
  const int bx = wg & 31, by = (wg >> 5) & 7, z = wg >> 8;
  const int mBase = bx * 128;
  const int nBase = by * 128;
  const u16* Bmat = Wbf3 + z * 1048576;
  const float* bias = (z == 0) ? bq : (z == 1) ? bk : bv;

  const int ci1 = tid, ci2 = tid + 256;
  const int r1 = ci1 >> 2, c1 = ci1 & 3, cc1 = c1 ^ ((r1 >> 1) & 3);
  const int r2 = ci2 >> 2, c2 = ci2 & 3, cc2 = c2 ^ ((r2 >> 1) & 3);

  f32x4 acc[4][4];
#pragma unroll
  for (int i = 0; i < 4; ++i)
#pragma unroll
    for (int j = 0; j < 4; ++j) acc[i][j] = {0.f, 0.f, 0.f, 0.f};

  for (int k0 = 0; k0 < 1024; k0 += 32) {
    async16(As + ci1 * 8, Xbf + (mBase + r1) * 1024 + k0 + cc1 * 8);
    async16(As + ci2 * 8, Xbf + (mBase + r2) * 1024 + k0 + cc2 * 8);
    async16(Bs + ci1 * 8, Bmat + (nBase + r1) * 1024 + k0 + cc1 * 8);
    async16(Bs + ci2 * 8, Bmat + (nBase + r2) * 1024 + k0 + cc2 * 8);
    __syncthreads();
    s16x8 a[4], b[4];
#pragma unroll
    for (int f = 0; f < 4; ++f) {
      int rl = wr * 64 + f * 16 + l15;
      a[f] = *(const s16x8*)(As + rl * 32 + ((l4 ^ ((rl >> 1) & 3)) * 8));
    }
#pragma unroll
    for (int f = 0; f < 4; ++f) {
      int rl = wc * 64 + f * 16 + l15;
      b[f] = *(const s16x8*)(Bs + rl * 32 + ((l4 ^ ((rl >> 1) & 3)) * 8));
    }
#pragma unroll
    for (int i = 0; i < 4; ++i)
#pragma unroll
      for (int j = 0; j < 4; ++j)
        acc[i][j] = __builtin_amdgcn_mfma_f32_16x16x32_bf16(a[i], b[j], acc[i][j], 0, 0, 0);
    __syncthreads();
  }

  const float scale = (z == 0) ? 0.125f : 1.0f;
  if (z < 2) {
    u16* dst = (z == 0) ? Qbf : Kbf;
#pragma unroll
    for (int i = 0; i < 4; ++i)
#pragma unroll
      for (int j = 0; j < 4; ++j) {
        int ng = nBase + wc * 64 + j * 16 + l15;
        int h = ng >> 6, d = ng & 63;
        float bb = bias[ng];
#pragma unroll
        for (int r = 0; r < 4; ++r) {
          int mg = mBase + wr * 64 + i * 16 + l4 * 4 + r;
          int bbi = mg >> 11, s = mg & 2047;
          dst[(((bbi * 16 + h) * 2048 + s) * 64) + d] = f2bf((acc[i][j][r] + bb) * scale);
        }
      }
  } else {
    // V: transpose in LDS with per-64-tile pi permutation on the s-dim.
    // s64 = i*16 + l4*4 + r  ->  pi(s64) = 16*l4 + 4*r + i; block = wr.
    u16* ct = smem;
#pragma unroll
    for (int i = 0; i < 4; ++i)
#pragma unroll
      for (int j = 0; j < 4; ++j) {
        int nl = wc * 64 + j * 16 + l15;
        float bb = bias[nBase + nl];
        int base = nl * 136 + wr * 64 + 16 * l4 + i;
#pragma unroll
        for (int r = 0; r < 4; ++r)
          ct[base + 4 * r] = f2bf(acc[i][j][r] + bb);
      }
    __syncthreads();
#pragma unroll
    for (int it = 0; it < 8; ++it) {
      int ci = tid + it * 256;
      int nl = ci >> 4, m8 = ci & 15;
      int ng = nBase + nl, mg = mBase + m8 * 8;
      int h = ng >> 6, d = ng & 63;
      int bbi = mg >> 11, s = mg & 2047;
      s16x8 v = *(const s16x8*)(ct + nl * 136 + m8 * 8);
      *(s16x8*)(VtB + (((bbi * 16 + h) * 64 + d) * 2048) + s) = v;
    }
  }
}

// ---------------------------------------------------------------------------
// Fused attention v5. Block = 64 q-rows x one bh, 4 waves (16 q-rows each).
//  - K AND V: LDS double-buffered via global_load_lds (stage kt+1 -> compute
//    kt -> vmcnt(0)+barrier).  [R10-verified]
//  - mask: direct global uint2 per (row, kt).
//  - P: TRUNCATION pack, plain C ((b0>>16)|(b1&0xffff0000)) -> scalar u32
//    stores into u32 LDS; read u32x4 + bit_cast; sched_barrier(0) fence.
//    Same element type on write and read => no TBAA surface; no asm.
//  - XCD chunk swizzle: 4 bh per XCD -> K/V L2-resident.  [R9-verified]
// LDS: Kb 16KB + Vb 16KB + Pls 9KB = 41984 B.
// ---------------------------------------------------------------------------
__global__ __launch_bounds__(256, 4) void attn_kernel(
    const u16* __restrict__ Qbf, const u16* __restrict__ Kbf,
    const u16* __restrict__ Vt, const u32* __restrict__ maskbits,
    float* __restrict__ out) {
  __shared__ u16 Kb[2][4096];               // [64 keys][64 d], XOR-swizzled
  __shared__ u16 Vb[2][4096];               // [64 d][64 pi-keys], XOR-swizzled
  __shared__ __align__(16) u32 Pls[4][576]; // per-wave P: [16 qrow][36 u32]

  const int tid  = threadIdx.x;
  const int lane = tid & 63;
  const int w    = tid >> 6;
  const int l15 = lane & 15, l4 = lane >> 4;

  // bijective XCD chunk swizzle over the 1024-block grid (1024 % 8 == 0)
  const int lin = blockIdx.x + 32 * blockIdx.y;
  const int wg  = (lin & 7) * 128 + (lin >> 3);
  const int qt = wg & 31;
  const int bh = wg >> 5;
  const int qbase = qt * 64;

  const int qrow = qbase + w * 16 + l15;
  const u16* qp = Qbf + ((bh * 2048 + qrow) * 64) + l4 * 8;
  s16x8 qa0 = *(const s16x8*)(qp);
  s16x8 qa1 = *(const s16x8*)(qp + 32);

  // per-thread mask row pointers (4 C-rows: qrow = w*16 + l4*4 + r)
  const u32* mrow[4];
#pragma unroll
  for (int r = 0; r < 4; ++r)
    mrow[r] = maskbits + (qbase + w * 16 + l4 * 4 + r) * 64;

  const f32x4 fzero = {0.f, 0.f, 0.f, 0.f};
  f32x4 acc[4];
#pragma unroll
  for (int d = 0; d < 4; ++d) acc[d] = fzero;
  float rs[4] = {0.f, 0.f, 0.f, 0.f};

  const int rkA = tid >> 3, cA = tid & 7, csA = cA ^ (rkA & 7);
  const int ci2 = tid + 256;
  const int rkB = ci2 >> 3, cB = ci2 & 7, csB = cB ^ (rkB & 7);
  const u16* kgbase = Kbf + (size_t)(bh * 2048) * 64;
  const u16* vgbase = Vt + (size_t)(bh * 64) * 2048;

  // prologue: stage K+V tile 0
  async16(Kb[0] + tid * 8, kgbase + rkA * 64 + csA * 8);
  async16(Kb[0] + ci2 * 8, kgbase + rkB * 64 + csB * 8);
  async16(Vb[0] + tid * 8, vgbase + rkA * 2048 + csA * 8);
  async16(Vb[0] + ci2 * 8, vgbase + rkB * 2048 + csB * 8);
  asm volatile("s_waitcnt vmcnt(0)" ::: "memory");
  __syncthreads();

  u32* Pw = Pls[w];

  for (int kt = 0; kt < 32; ++kt) {
    const int kb = kt * 64;
    const int cur = kt & 1;

    // mask words for this tile
    uint2 mw2[4];
#pragma unroll
    for (int r = 0; r < 4; ++r)
      mw2[r] = *(const uint2*)(mrow[r] + kt * 2);

    // prefetch next K+V tile into the other buffer (flies during compute)
    if (kt < 31) {
      const u16* kg = kgbase + (kb + 64) * 64;
      const u16* vg = vgbase + kb + 64;
      async16(Kb[cur ^ 1] + tid * 8, kg + rkA * 64 + csA * 8);
      async16(Kb[cur ^ 1] + ci2 * 8, kg + rkB * 64 + csB * 8);
      async16(Vb[cur ^ 1] + tid * 8, vg + rkA * 2048 + csA * 8);
      async16(Vb[cur ^ 1] + ci2 * 8, vg + rkB * 2048 + csB * 8);
    }

    // QK^T from Kb[cur]
    f32x4 sc[4];
#pragma unroll
    for (int fn = 0; fn < 4; ++fn) {
      int key = fn * 16 + l15;
      s16x8 kf0 = *(const s16x8*)(Kb[cur] + key * 64 + ((l4 ^ (key & 7)) * 8));
      s16x8 kf1 = *(const s16x8*)(Kb[cur] + key * 64 + (((l4 + 4) ^ (key & 7)) * 8));
      sc[fn] = __builtin_amdgcn_mfma_f32_16x16x32_bf16(qa0, kf0, fzero, 0, 0, 0);
      sc[fn] = __builtin_amdgcn_mfma_f32_16x16x32_bf16(qa1, kf1, sc[fn], 0, 0, 0);
    }

    // mask * exp; truncation-pack P pairs (keys fn*16+l15 -> pi-pos 4*l15+fn)
    // u32 col l15*2 holds bf16 positions {4*l15 (lo=p0), 4*l15+1 (hi=p1)}.
#pragma unroll
    for (int r = 0; r < 4; ++r) {
      float p[4];
#pragma unroll
      for (int fn = 0; fn < 4; ++fn) {
        u32 word = (fn < 2) ? mw2[r].x : mw2[r].y;
        u32 bp = (u32)((fn & 1) * 16 + l15);
        float sv = ((word >> bp) & 1u) ? sc[fn][r] : 0.0f;
        p[fn] = __expf(sv);
      }
      rs[r] += (p[0] + p[1]) + (p[2] + p[3]);
      u32 b0 = __builtin_bit_cast(u32, p[0]);
      u32 b1 = __builtin_bit_cast(u32, p[1]);
      u32 b2 = __builtin_bit_cast(u32, p[2]);
      u32 b3 = __builtin_bit_cast(u32, p[3]);
      u32* wp = Pw + (l4 * 4 + r) * 36 + l15 * 2;
      wp[0] = (b0 >> 16) | (b1 & 0xffff0000u);
      wp[1] = (b2 >> 16) | (b3 & 0xffff0000u);
    }

    __builtin_amdgcn_sched_barrier(0);   // scheduling fence (belt+suspenders)

    // PV (A = P from per-wave u32 LDS, B = V from Vb[cur])
    u32x4 t0 = *(const u32x4*)(Pw + l15 * 36 + l4 * 4);
    u32x4 t1 = *(const u32x4*)(Pw + l15 * 36 + 16 + l4 * 4);
    s16x8 pa0 = __builtin_bit_cast(s16x8, t0);
    s16x8 pa1 = __builtin_bit_cast(s16x8, t1);
#pragma unroll
    for (int df = 0; df < 4; ++df) {
      int dl = df * 16 + l15;
      s16x8 vf0 = *(const s16x8*)(Vb[cur] + dl * 64 + ((l4 ^ (dl & 7)) * 8));
      s16x8 vf1 = *(const s16x8*)(Vb[cur] + dl * 64 + (((l4 + 4) ^ (dl & 7)) * 8));
      acc[df] = __builtin_amdgcn_mfma_f32_16x16x32_bf16(pa0, vf0, acc[df], 0, 0, 0);
      acc[df] = __builtin_amdgcn_mfma_f32_16x16x32_bf16(pa1, vf1, acc[df], 0, 0, 0);
    }

    asm volatile("s_waitcnt vmcnt(0)" ::: "memory");   // next K+V tile staged
    __syncthreads();
  }

#pragma unroll
  for (int r = 0; r < 4; ++r) {
    float v = rs[r];
    v += __shfl_xor(v, 1); v += __shfl_xor(v, 2);
    v += __shfl_xor(v, 4); v += __shfl_xor(v, 8);
    rs[r] = 1.0f / v;
  }
  const int b = bh >> 4, h = bh & 15;
#pragma unroll
  for (int df = 0; df < 4; ++df) {
    int col = h * 64 + df * 16 + l15;
#pragma unroll
    for (int r = 0; r < 4; ++r) {
      int qg = qbase + w * 16 + l4 * 4 + r;
      out[(b * 2048 + qg) * 1024 + col] = acc[df][r] * rs[r];
    }
  }
}

// ---------------------------------------------------------------------------
extern "C" void kernel_launch(void* const* d_in, const int* in_sizes, int n_in,
                              void* d_out, int out_size, void* d_ws, size_t ws_size,
                              hipStream_t stream) {
  const float* hs = (const float*)d_in[0];
  const float* Wq = (const float*)d_in[1];
  const float* bq = (const float*)d_in[2];
  const float* Wk = (const float*)d_in[3];
  const float* bk = (const float*)d_in[4];
  const float* Wv = (const float*)d_in[5];
  const float* bv = (const float*)d_in[6];
  float* out = (float*)d_out;
  char* ws = (char*)d_ws;

  u32* maskbits = (u32*)(ws);                       // 512 KB
  u16* Xbf  = (u16*)(ws + 524288);                  // 8 MB  [4096][1024]
  u16* Wbf3 = (u16*)(ws + 524288 + 8388608);        // 6 MB  3x[1024][1024]
  u16* Qbf  = (u16*)(ws + 15204352);                // 8 MB  [bh][s][d]
  u16* Kbf  = (u16*)(ws + 23592960);                // 8 MB  [bh][s][d]
  u16* Vt   = (u16*)(ws + 31981568);                // 8 MB  [bh][d][s'] pi-layout

  cast_all<<<7168, 256, 0, stream>>>(hs, Wq, Wk, Wv, Xbf, Wbf3);
  mask_kernel<<<2048, 256, 0, stream>>>(maskbits);
  gemm_qkv<<<dim3(32, 8, 3), 256, 0, stream>>>(Xbf, Wbf3, bq, bk, bv, Qbf, Kbf, Vt);
  attn_kernel<<<dim3(32, 32), 256, 0, stream>>>(Qbf, Kbf, Vt, maskbits, out);
}